// Round 3
// baseline (757.125 us; speedup 1.0000x reference)
//
#include <hip/hip_runtime.h>

// CIN (xDeepFM) fused kernel set for MI355X.
// Layer op: out[b,s,d] = relu( sum_{f,g} x[b,f,d]*h[b,g,d]*W[f*Fk+g, s] + bias[s] )
// Viewed as GEMM over rows m=(b,d): out_row = W^T z_row, z_row = outer(x_row, h_row).
//
// Shapes: B=2048, D=16, F0=39, S=128 for all 3 layers.
//   L0: h=x,  Fk=39, K=1521 (K-loop padded to 1536; pad rows are zero on both sides)
//   L1: h=h1, Fk=64, K=2496
//   L2: h=h2, Fk=64, K=2496
// Output (B x 256): d_out[b,0:64]=sum_d out0[b,64:128,d]; [64:128]=sum_d out1[b,64:128,d];
//                   [128:256]=sum_d out2[b,0:128,d].
//
// Structure (held from round 1, re-audited round 2): 64 rows x 128 cols per
// block, 256 threads, thread tile 4 rows x (4+4) cols (two float4 column
// groups 64 apart -> 2-lanes/bank w-reads = free). 3 ds_read_b128 per 32 FMAs
// -> FMA-bound inner loop. xs/hs padded to odd strides (41/65) so
// column-strided z-build reads are conflict-free. LDS 74.5KB -> 2 blocks/CU;
// grid 512 = exactly co-resident.

#define F0C 39
#define DDIM 16
#define RT 64      // rows (b,d pairs) per block
#define KT 64      // k per LDS tile

template<int FK, int K, int COL_OFF, bool WRITE_H, bool DIRECT_ALL>
__launch_bounds__(256, 2)
__global__ void cin_layer(const float* __restrict__ xg,
                          const float* __restrict__ hg,
                          const float* __restrict__ Wg,
                          const float* __restrict__ bg,
                          float* __restrict__ h_out,
                          float* __restrict__ outg) {
    __shared__ float xs[RT][41];        // 10.25 KB (odd stride: conflict-free col reads)
    __shared__ float hs[RT][65];        // 16.25 KB (unused for FK==39)
    __shared__ float Ws[KT][128];       // 32 KB
    __shared__ float zs[KT][RT];        // 16 KB (reused as reduction scratch)

    const int tid = threadIdx.x;
    const int ts  = tid & 15;           // col group: s = ts*4..+3 and 64+ts*4..+3
    const int tr  = tid >> 4;           // row group: r = tr*4..+3
    const int m0  = blockIdx.x * RT;    // first (b,d) row; b=m>>4, d=m&15

    // ---- stage x rows: xs[r][f] = x[b,f,d]; col 39 zeroed (kills L0 K-pad) ----
    for (int idx = tid; idx < RT * 40; idx += 256) {
        int r = idx / 40, f = idx - r * 40;
        int m = m0 + r;
        float v = 0.f;
        if (f < F0C) v = xg[((m >> 4) * F0C + f) * DDIM + (m & 15)];
        xs[r][f] = v;
    }
    // ---- stage h rows (layers 1,2): hs[r][g] = h_ws[(m0+r)*64 + g] ----
    if constexpr (FK == 64) {
        #pragma unroll
        for (int j = 0; j < 16; ++j) {
            int idx = j * 256 + tid;
            int r = idx >> 6, g = idx & 63;
            hs[r][g] = hg[(m0 + r) * 64 + g];
        }
    }

    float acc[4][8];
    #pragma unroll
    for (int i = 0; i < 4; ++i)
        #pragma unroll
        for (int j = 0; j < 8; ++j) acc[i][j] = 0.f;

    const float4* Wg4 = reinterpret_cast<const float4*>(Wg);

    for (int kt = 0; kt < K; kt += KT) {
        __syncthreads();
        // ---- stage W tile: Ws[kl][s], zero-padded past K (L0 only) ----
        #pragma unroll
        for (int j = 0; j < 8; ++j) {
            int lin = j * 256 + tid;            // float4 index in 64x128 tile
            int kl  = lin >> 5;                 // 32 float4 per k-row
            float4 v = make_float4(0.f, 0.f, 0.f, 0.f);
            if ((K % KT == 0) || (kt + kl < K)) v = Wg4[kt * 32 + lin];
            reinterpret_cast<float4*>(Ws)[lin] = v;
        }
        // ---- stage z tile: zs[kl][r] = x[r][f]*h[r][g], k = kt+kl = f*FK+g ----
        // per wave: kl uniform, r = lane -> column reads of xs/hs (odd stride, free)
        #pragma unroll
        for (int j = 0; j < 16; ++j) {
            int idx = j * 256 + tid;
            int kl = idx >> 6, r = idx & 63;
            int k = kt + kl;
            int f = k / FK, g = k - f * FK;     // FK=64 -> shifts; FK=39 -> magic mul
            float xv = xs[r][f];                // L0 pad k>=1521: f==39 -> 0
            float hv = (FK == 39) ? xs[r][g] : hs[r][g];
            zs[kl][r] = xv * hv;
        }
        __syncthreads();
        // ---- inner: 3 x ds_read_b128 + 32 FMA per k ----
        #pragma unroll 8
        for (int kl = 0; kl < KT; ++kl) {
            float4 w0 = *reinterpret_cast<const float4*>(&Ws[kl][ts * 4]);
            float4 w1 = *reinterpret_cast<const float4*>(&Ws[kl][64 + ts * 4]);
            float4 z  = *reinterpret_cast<const float4*>(&zs[kl][tr * 4]);
            float zv[4] = {z.x, z.y, z.z, z.w};
            #pragma unroll
            for (int i = 0; i < 4; ++i) {
                acc[i][0] += zv[i] * w0.x; acc[i][1] += zv[i] * w0.y;
                acc[i][2] += zv[i] * w0.z; acc[i][3] += zv[i] * w0.w;
                acc[i][4] += zv[i] * w1.x; acc[i][5] += zv[i] * w1.y;
                acc[i][6] += zv[i] * w1.z; acc[i][7] += zv[i] * w1.w;
            }
        }
    }

    // ---- epilogue: bias + relu ----
    const int s0a = ts * 4;             // group A cols (0..63)  -> h part
    const int s0b = 64 + ts * 4;        // group B cols (64..127) -> direct (L0/L1)
    float4 bva = *reinterpret_cast<const float4*>(&bg[s0a]);
    float4 bvb = *reinterpret_cast<const float4*>(&bg[s0b]);
    float val[4][8];
    #pragma unroll
    for (int i = 0; i < 4; ++i) {
        val[i][0] = fmaxf(acc[i][0] + bva.x, 0.f);
        val[i][1] = fmaxf(acc[i][1] + bva.y, 0.f);
        val[i][2] = fmaxf(acc[i][2] + bva.z, 0.f);
        val[i][3] = fmaxf(acc[i][3] + bva.w, 0.f);
        val[i][4] = fmaxf(acc[i][4] + bvb.x, 0.f);
        val[i][5] = fmaxf(acc[i][5] + bvb.y, 0.f);
        val[i][6] = fmaxf(acc[i][6] + bvb.z, 0.f);
        val[i][7] = fmaxf(acc[i][7] + bvb.w, 0.f);
    }

    // ---- h part: out[:, 0:64] -> h_out (next layer's h) ----
    if constexpr (WRITE_H) {
        #pragma unroll
        for (int i = 0; i < 4; ++i) {
            float4 v = make_float4(val[i][0], val[i][1], val[i][2], val[i][3]);
            *reinterpret_cast<float4*>(&h_out[(m0 + tr * 4 + i) * 64 + s0a]) = v;
        }
    }

    // ---- direct part: sum this thread's 4 rows (4 consecutive d of one b) ----
    float pa[4], pb[4];
    #pragma unroll
    for (int j = 0; j < 4; ++j) {
        pa[j] = val[0][j] + val[1][j] + val[2][j] + val[3][j];
        pb[j] = val[0][4 + j] + val[1][4 + j] + val[2][4 + j] + val[3][4 + j];
    }

    __syncthreads();                    // zs free now; reuse as reduction scratch
    float4* redA = reinterpret_cast<float4*>(&zs[0][0]);   // [16][16] float4
    float4* redB = redA + 256;                              // [16][16] float4
    redA[tr * 16 + ts] = make_float4(pa[0], pa[1], pa[2], pa[3]);
    redB[tr * 16 + ts] = make_float4(pb[0], pb[1], pb[2], pb[3]);
    __syncthreads();

    if ((tr & 3) == 0) {                // tr in {0,4,8,12}: one b each, finish d-sum
        int bb = (m0 >> 4) + (tr >> 2);
        float4 b0v = redB[(tr + 0) * 16 + ts];
        float4 b1v = redB[(tr + 1) * 16 + ts];
        float4 b2v = redB[(tr + 2) * 16 + ts];
        float4 b3v = redB[(tr + 3) * 16 + ts];
        float4 sB = make_float4(b0v.x + b1v.x + b2v.x + b3v.x,
                                b0v.y + b1v.y + b2v.y + b3v.y,
                                b0v.z + b1v.z + b2v.z + b3v.z,
                                b0v.w + b1v.w + b2v.w + b3v.w);
        *reinterpret_cast<float4*>(&outg[bb * 256 + s0b + COL_OFF]) = sB;
        if constexpr (DIRECT_ALL) {
            float4 a0v = redA[(tr + 0) * 16 + ts];
            float4 a1v = redA[(tr + 1) * 16 + ts];
            float4 a2v = redA[(tr + 2) * 16 + ts];
            float4 a3v = redA[(tr + 3) * 16 + ts];
            float4 sA = make_float4(a0v.x + a1v.x + a2v.x + a3v.x,
                                    a0v.y + a1v.y + a2v.y + a3v.y,
                                    a0v.z + a1v.z + a2v.z + a3v.z,
                                    a0v.w + a1v.w + a2v.w + a3v.w);
            *reinterpret_cast<float4*>(&outg[bb * 256 + s0a + COL_OFF]) = sA;
        }
    }
}

extern "C" void kernel_launch(void* const* d_in, const int* in_sizes, int n_in,
                              void* d_out, int out_size, void* d_ws, size_t ws_size,
                              hipStream_t stream) {
    const float* x  = (const float*)d_in[0];
    const float* W0 = (const float*)d_in[1];
    const float* W1 = (const float*)d_in[2];
    const float* W2 = (const float*)d_in[3];
    const float* b0 = (const float*)d_in[4];
    const float* b1 = (const float*)d_in[5];
    const float* b2 = (const float*)d_in[6];
    float* out = (float*)d_out;

    float* h1 = (float*)d_ws;                    // (B*D) x 64 = 8 MB
    float* h2 = h1 + 2048 * DDIM * 64;           // 8 MB

    dim3 grid(2048 * DDIM / RT), block(256);
    // L0: h = x (Fk=39, K=1521); direct s in [64,128) -> cols 0..63
    cin_layer<39, 1521, -64, true,  false><<<grid, block, 0, stream>>>(x, x,  W0, b0, h1, out);
    // L1: h = h1 (Fk=64, K=2496); direct s in [64,128) -> cols 64..127
    cin_layer<64, 2496,   0, true,  false><<<grid, block, 0, stream>>>(x, h1, W1, b1, h2, out);
    // L2: h = h2; all 128 s -> cols 128..255
    cin_layer<64, 2496, 128, false, true ><<<grid, block, 0, stream>>>(x, h2, W2, b2, nullptr, out);
}

// Round 4
// 497.232 us; speedup vs baseline: 1.5227x; 1.5227x over previous
//
#include <hip/hip_runtime.h>

// CIN (xDeepFM) — split-bf16 MFMA version for MI355X (gfx950).
//
// Layer op: out[b,s,d] = relu( sum_{f,g} x[b,f,d]*h[b,g,d]*W[f*Fk+g, s] + b[s] )
// GEMM view over rows m=(b,d): out_row = z_row * W, z_row[k] = x[f]*h[g], k=f*FK+g.
// All layers unified to FK=64, K=2496 (L0: g>=39 zero-padded in both h and packed W).
//
// Precision: split-bf16 3-term: z*W ~= zh*Wh + zh*Wl + zl*Wh (rel err ~2^-17).
// MFMA: v_mfma_f32_16x16x32_bf16, wave computes 16 rows x 128 cols.
// A-frag (z) is computed IN REGISTERS by the consuming lane (thread t=w*64+l is
// lane l of wave w and owns row w*16+(l&15), k-chunk (l>>4)*8) -> no z LDS, no
// barriers in the K-loop. B-frag (W) pre-packed by prep kernel into per-lane
// order [k32step][colfrag][lane][8] so each read is one coalesced dwordx4.

typedef __bf16 bf16x8 __attribute__((ext_vector_type(8)));
typedef float  f32x4  __attribute__((ext_vector_type(4)));

#define KSTEPS 78            // 2496 / 32
#define PACKN  319488        // 2496*128 packed elements per layer

// ---------------- prep: pack W (fp32 [K][128]) -> hi/lo bf16 fragment order ----
template<bool L0>
__global__ void pack_w(const float* __restrict__ Wsrc,
                       unsigned short* __restrict__ hi,
                       unsigned short* __restrict__ lo) {
    int idx = blockIdx.x * 256 + threadIdx.x;
    if (idx >= PACKN) return;
    int j    = idx & 7;
    int lane = (idx >> 3) & 63;
    int cf   = (idx >> 9) & 7;
    int step = idx >> 12;
    int k = step * 32 + (lane >> 4) * 8 + j;     // k-slot this element feeds
    int s = cf * 16 + (lane & 15);
    float v;
    if constexpr (L0) {
        int f = k >> 6, g = k & 63;              // padded k = f*64+g
        v = (g < 39) ? Wsrc[(f * 39 + g) * 128 + s] : 0.f;
    } else {
        v = Wsrc[k * 128 + s];
    }
    __bf16 h = (__bf16)v;
    __bf16 lw = (__bf16)(v - (float)h);
    hi[idx] = __builtin_bit_cast(unsigned short, h);
    lo[idx] = __builtin_bit_cast(unsigned short, lw);
}

// ---------------- main: one CIN layer ----------------
// SRC_X: h comes from x (layer 0, g-padded); else from hg (fp32 [M][64]).
template<int SRC_X, int COL_OFF, bool WRITE_H, bool DIRECT_ALL>
__launch_bounds__(256, 4)
__global__ void cin_mfma(const float* __restrict__ xg,
                         const float* __restrict__ hg,
                         const unsigned short* __restrict__ Whi,
                         const unsigned short* __restrict__ Wlo,
                         const float* __restrict__ bg,
                         float* __restrict__ h_out,
                         float* __restrict__ outg) {
    __shared__ float xs[64][41];   // x rows (f side), odd stride: conflict-free col reads
    __shared__ float hs[64][68];   // h rows (g side), stride 68: 16B-aligned rows

    const int tid = threadIdx.x;
    const int w   = tid >> 6;      // wave 0..3
    const int l   = tid & 63;      // lane
    const int m0  = blockIdx.x * 64;   // first (b,d) row; b=m>>4, d=m&15

    // ---- stage x rows: xs[r][f] = x[b, f, d] ----
    for (int idx = tid; idx < 64 * 40; idx += 256) {
        int r = idx / 40, f = idx - r * 40;
        if (f < 39) {
            int m = m0 + r;
            xs[r][f] = xg[((m >> 4) * 39 + f) * 16 + (m & 15)];
        }
    }
    // ---- stage h rows: hs[r][g] (g>=39 zero for layer 0) ----
    if constexpr (SRC_X) {
        for (int idx = tid; idx < 64 * 64; idx += 256) {
            int r = idx >> 6, g = idx & 63;
            int m = m0 + r;
            hs[r][g] = (g < 39) ? xg[((m >> 4) * 39 + g) * 16 + (m & 15)] : 0.f;
        }
    } else {
        for (int idx = tid; idx < 64 * 16; idx += 256) {
            int r = idx >> 4, c = idx & 15;
            float4 v = *reinterpret_cast<const float4*>(&hg[(m0 + r) * 64 + c * 4]);
            *reinterpret_cast<float4*>(&hs[r][c * 4]) = v;
        }
    }
    __syncthreads();               // only barrier in the kernel

    const int row = w * 16 + (l & 15);   // this lane's A row
    const int kb  = (l >> 4) * 8;        // this lane's k-chunk base within a k32 step

    f32x4 acc[8];
    #pragma unroll
    for (int c = 0; c < 8; ++c) acc[c] = (f32x4){0.f, 0.f, 0.f, 0.f};

    const uint4* Bhi = reinterpret_cast<const uint4*>(Whi);   // 16B granules
    const uint4* Blo = reinterpret_cast<const uint4*>(Wlo);

    for (int step = 0; step < KSTEPS; ++step) {
        const int kt = step * 32;
        const int f  = kt >> 6;                 // uniform over wave (kb<=24, +7<=63)
        const int g0 = (kt & 63) + kb;          // 8-aligned, no 64-wrap within chunk
        // ---- build A fragments (z hi/lo) in registers ----
        float xv = xs[row][f];
        float4 h4a = *reinterpret_cast<const float4*>(&hs[row][g0]);
        float4 h4b = *reinterpret_cast<const float4*>(&hs[row][g0 + 4]);
        float hv[8] = {h4a.x, h4a.y, h4a.z, h4a.w, h4b.x, h4b.y, h4b.z, h4b.w};
        bf16x8 ah, al;
        #pragma unroll
        for (int j = 0; j < 8; ++j) {
            float p = xv * hv[j];
            __bf16 ph = (__bf16)p;
            ah[j] = ph;
            al[j] = (__bf16)(p - (float)ph);
        }
        // ---- B frags: coalesced dwordx4 from packed W (L1/L2 resident) ----
        const uint4* bh = Bhi + (size_t)(step * 8) * 64 + l;
        const uint4* bl = Blo + (size_t)(step * 8) * 64 + l;
        #pragma unroll
        for (int cf = 0; cf < 8; ++cf) {
            bf16x8 bhv = __builtin_bit_cast(bf16x8, bh[cf * 64]);
            bf16x8 blv = __builtin_bit_cast(bf16x8, bl[cf * 64]);
            acc[cf] = __builtin_amdgcn_mfma_f32_16x16x32_bf16(ah, bhv, acc[cf], 0, 0, 0);
            acc[cf] = __builtin_amdgcn_mfma_f32_16x16x32_bf16(ah, blv, acc[cf], 0, 0, 0);
            acc[cf] = __builtin_amdgcn_mfma_f32_16x16x32_bf16(al, bhv, acc[cf], 0, 0, 0);
        }
    }

    // ---- epilogue: bias + relu; h-part to h_out; d-sum to d_out ----
    // C/D layout (m89): col = lane&15, row = (lane>>4)*4 + reg.
    const int ls = l & 15;
    const int lg = l >> 4;
    const int b  = (m0 >> 4) + w;        // wave's 16 rows = one batch element's 16 d's
    #pragma unroll
    for (int cf = 0; cf < 8; ++cf) {
        int s = cf * 16 + ls;
        float bias = bg[s];
        float v0 = fmaxf(acc[cf][0] + bias, 0.f);
        float v1 = fmaxf(acc[cf][1] + bias, 0.f);
        float v2 = fmaxf(acc[cf][2] + bias, 0.f);
        float v3 = fmaxf(acc[cf][3] + bias, 0.f);
        if (WRITE_H && s < 64) {
            int base = m0 + w * 16 + lg * 4;
            h_out[(base + 0) * 64 + s] = v0;
            h_out[(base + 1) * 64 + s] = v1;
            h_out[(base + 2) * 64 + s] = v2;
            h_out[(base + 3) * 64 + s] = v3;
        }
        float t = v0 + v1 + v2 + v3;
        t += __shfl_xor(t, 16, 64);
        t += __shfl_xor(t, 32, 64);
        if (DIRECT_ALL || s >= 64) {
            if (l < 16) outg[b * 256 + s + COL_OFF] = t;
        }
    }
}

extern "C" void kernel_launch(void* const* d_in, const int* in_sizes, int n_in,
                              void* d_out, int out_size, void* d_ws, size_t ws_size,
                              hipStream_t stream) {
    const float* x  = (const float*)d_in[0];
    const float* W0 = (const float*)d_in[1];
    const float* W1 = (const float*)d_in[2];
    const float* W2 = (const float*)d_in[3];
    const float* b0 = (const float*)d_in[4];
    const float* b1 = (const float*)d_in[5];
    const float* b2 = (const float*)d_in[6];
    float* out = (float*)d_out;

    char* ws = (char*)d_ws;
    float* h1 = (float*)ws;                          // 8 MB  (32768 x 64 f32)
    float* h2 = (float*)(ws + (8u << 20));           // 8 MB
    // packed W: 6 arrays of 640KB each starting at 16MB
    unsigned short* W0h = (unsigned short*)(ws + (16u << 20));
    unsigned short* W0l = W0h + 327680;
    unsigned short* W1h = W0h + 2 * 327680;
    unsigned short* W1l = W0h + 3 * 327680;
    unsigned short* W2h = W0h + 4 * 327680;
    unsigned short* W2l = W0h + 5 * 327680;

    dim3 pb(256), pg((PACKN + 255) / 256);
    pack_w<true ><<<pg, pb, 0, stream>>>(W0, W0h, W0l);
    pack_w<false><<<pg, pb, 0, stream>>>(W1, W1h, W1l);
    pack_w<false><<<pg, pb, 0, stream>>>(W2, W2h, W2l);

    dim3 grid(512), block(256);
    // L0: h = x (padded); direct s in [64,128) -> cols 0..63
    cin_mfma<1, -64, true,  false><<<grid, block, 0, stream>>>(x, nullptr, W0h, W0l, b0, h1, out);
    // L1: h = h1; direct s in [64,128) -> cols 64..127
    cin_mfma<0,   0, true,  false><<<grid, block, 0, stream>>>(x, h1,      W1h, W1l, b1, h2, out);
    // L2: h = h2; all 128 s -> cols 128..255
    cin_mfma<0, 128, false, true ><<<grid, block, 0, stream>>>(x, h2,      W2h, W2l, b2, nullptr, out);
}

// Round 5
// 458.582 us; speedup vs baseline: 1.6510x; 1.0843x over previous
//
#include <hip/hip_runtime.h>

// CIN (xDeepFM) — split-bf16 MFMA v2 for MI355X (gfx950).
//
// Layer op: out[b,s,d] = relu( sum_{f,g} x[b,f,d]*h[b,g,d]*W[f*Fk+g, s] + b[s] )
// GEMM rows m=(b,d): out_row = z_row * W, z_row[k] = x[f]*h[g], k = f*64+g
// (all layers unified to FK=64, K=2496; L0 g>=39 zero-padded on both sides).
//
// v2 vs v1 (round 4): v1 was L2-BW-bound — each wave streamed 1.28MB of packed
// W from L2 (2.6GB/dispatch). v2: (a) 32x32x16 MFMA, wave = 32 rows x 128 cols
// (per-row B traffic halved); (b) W staged to LDS per block, double-buffered
// via global_load_lds, one barrier per K16-step (L2 W-traffic 8x lower);
// (c) z (A-frag) still computed in-register by the consuming lane -> no z LDS.
// Numerics: 3-term split zh*Wh + zh*Wl + zl*Wh (unchanged from verified v1).
// Block: 256 thr = 4 waves = 128 rows; grid 256 = 1 block/CU.

typedef __bf16 bf16x8 __attribute__((ext_vector_type(8)));
typedef float  f32x16 __attribute__((ext_vector_type(16)));

#define NSTEP 156            // 2496 / 16
#define PACKN 319488         // 2496 * 128

// ---- prep: pack W (fp32 [K][128]) -> hi/lo bf16, 32x32 fragment order ----
// elem idx = ((step*4 + cf)*64 + lane)*8 + j ; k = step*16 + (lane>>5)*8 + j ;
// s = cf*32 + (lane&31)
template<bool L0>
__global__ void pack_w(const float* __restrict__ Wsrc,
                       unsigned short* __restrict__ hi,
                       unsigned short* __restrict__ lo) {
    int idx = blockIdx.x * 256 + threadIdx.x;
    if (idx >= PACKN) return;
    int j    = idx & 7;
    int lane = (idx >> 3) & 63;
    int cf   = (idx >> 9) & 3;
    int step = idx >> 11;
    int k = step * 16 + (lane >> 5) * 8 + j;
    int s = cf * 32 + (lane & 31);
    float v;
    if constexpr (L0) {
        int f = k >> 6, g = k & 63;
        v = (g < 39) ? Wsrc[(f * 39 + g) * 128 + s] : 0.f;
    } else {
        v = Wsrc[k * 128 + s];
    }
    __bf16 h = (__bf16)v;
    __bf16 lw = (__bf16)(v - (float)h);
    hi[idx] = __builtin_bit_cast(unsigned short, h);
    lo[idx] = __builtin_bit_cast(unsigned short, lw);
}

// ---- main: one CIN layer ----
template<int SRC_X, int COL_OFF, bool WRITE_H, bool DIRECT_ALL>
__launch_bounds__(256, 1)
__global__ void cin_mfma(const float* __restrict__ xg,
                         const float* __restrict__ hg,
                         const uint4* __restrict__ Whi,
                         const uint4* __restrict__ Wlo,
                         const float* __restrict__ bg,
                         float* __restrict__ h_out,
                         float* __restrict__ outg) {
    __shared__ __attribute__((aligned(16))) float xs[128][41];  // 21 KB
    __shared__ __attribute__((aligned(16))) float hs[128][68];  // 35 KB (16B rows)
    __shared__ uint4 WhL[2][256];   // 8 KB : [buf][cf*64 + lane]
    __shared__ uint4 WlL[2][256];   // 8 KB

    const int tid = threadIdx.x;
    const int w   = tid >> 6;       // wave 0..3 -> rows w*32..w*32+31
    const int l   = tid & 63;
    const int m0  = blockIdx.x * 128;     // first (b,d) row; b=m>>4, d=m&15
    const int b0  = m0 >> 4;              // 8 batch elems per block

    // ---- stage x rows: xs[bl*16+d][f] = x[b0+bl, f, d] (coalesced per 16 lanes) ----
    for (int idx = tid; idx < 8 * 39 * 16; idx += 256) {
        int bl_ = idx / 624, rem = idx - bl_ * 624;
        int f = rem >> 4, d = rem & 15;
        xs[bl_ * 16 + d][f] = xg[(((b0 + bl_) * 39 + f) << 4) + d];
    }
    // ---- stage h rows: hs[r][g] (L0: from x, g>=39 zero) ----
    if constexpr (SRC_X) {
        for (int idx = tid; idx < 128 * 64; idx += 256) {
            int r = idx >> 6, g = idx & 63;
            hs[r][g] = (g < 39) ? xg[(((b0 + (r >> 4)) * 39 + g) << 4) + (r & 15)] : 0.f;
        }
    } else {
        for (int idx = tid; idx < 128 * 16; idx += 256) {
            int r = idx >> 4, c = idx & 15;
            *reinterpret_cast<float4*>(&hs[r][c * 4]) =
                *reinterpret_cast<const float4*>(&hg[(m0 + r) * 64 + c * 4]);
        }
    }

    // ---- W staging: async global->LDS, wave-uniform LDS base + lane*16 ----
    auto stage = [&](int s, int b) {
        __builtin_amdgcn_global_load_lds((const unsigned int*)(Whi + s * 256 + w * 64 + l),
                                         (unsigned int*)&WhL[b][w * 64], 16, 0, 0);
        __builtin_amdgcn_global_load_lds((const unsigned int*)(Wlo + s * 256 + w * 64 + l),
                                         (unsigned int*)&WlL[b][w * 64], 16, 0, 0);
    };

    stage(0, 0);
    __syncthreads();    // covers xs/hs stores + step-0 W (vmcnt(0)+lgkmcnt(0) drain)

    f32x16 acc[4];
    #pragma unroll
    for (int c = 0; c < 4; ++c)
        #pragma unroll
        for (int i = 0; i < 16; ++i) acc[c][i] = 0.f;

    const int r    = l & 31;        // A row within tile / B,C col
    const int hb   = l >> 5;        // k-half select
    const int lrow = w * 32 + r;    // LDS row of this lane's A row
    int buf = 0;

    for (int step = 0; step < NSTEP; ++step) {
        if (step + 1 < NSTEP) stage(step + 1, buf ^ 1);   // issue early, drain at barrier
        const int f  = step >> 2;                         // wave-uniform field idx
        const int g0 = ((step & 3) << 4) + hb * 8;        // 8-aligned, no 64-wrap
        // ---- A frags (z hi/lo) in registers: k = step*16 + hb*8 + j ----
        float  xv  = xs[lrow][f];
        float4 h4a = *reinterpret_cast<const float4*>(&hs[lrow][g0]);
        float4 h4b = *reinterpret_cast<const float4*>(&hs[lrow][g0 + 4]);
        float hv[8] = {h4a.x, h4a.y, h4a.z, h4a.w, h4b.x, h4b.y, h4b.z, h4b.w};
        bf16x8 ah, al;
        #pragma unroll
        for (int j = 0; j < 8; ++j) {
            float p = xv * hv[j];
            __bf16 ph = (__bf16)p;
            ah[j] = ph;
            al[j] = (__bf16)(p - (float)ph);
        }
        // ---- B frags from LDS (contiguous 1KB/wave per read = conflict-free) ----
        #pragma unroll
        for (int cf = 0; cf < 4; ++cf) {
            bf16x8 bh = __builtin_bit_cast(bf16x8, WhL[buf][cf * 64 + l]);
            bf16x8 blv = __builtin_bit_cast(bf16x8, WlL[buf][cf * 64 + l]);
            acc[cf] = __builtin_amdgcn_mfma_f32_32x32x16_bf16(ah, bh,  acc[cf], 0, 0, 0);
            acc[cf] = __builtin_amdgcn_mfma_f32_32x32x16_bf16(ah, blv, acc[cf], 0, 0, 0);
            acc[cf] = __builtin_amdgcn_mfma_f32_32x32x16_bf16(al, bh,  acc[cf], 0, 0, 0);
        }
        __syncthreads();            // drains this wave's staging loads + LDS reads
        buf ^= 1;
    }

    // ---- epilogue. C/D 32x32 map (m74/m101): col = lane&31,
    // row = (reg&3) + 8*(reg>>2) + 4*(lane>>5).  Wave rows m0+w*32..+31 =
    // 2 batch elems (regs 0-7 -> b_base, regs 8-15 -> b_base+1). ----
    const int b_base = b0 + w * 2;
    #pragma unroll
    for (int cf = 0; cf < 4; ++cf) {
        int s = cf * 32 + r;
        float bias = bg[s];
        float v[16], s0 = 0.f, s1 = 0.f;
        #pragma unroll
        for (int reg = 0; reg < 16; ++reg) {
            float vv = fmaxf(acc[cf][reg] + bias, 0.f);
            v[reg] = vv;
            if (reg < 8) s0 += vv; else s1 += vv;
        }
        if (WRITE_H && s < 64) {
            #pragma unroll
            for (int reg = 0; reg < 16; ++reg) {
                int trow = (reg & 3) + 8 * (reg >> 2) + 4 * hb;
                h_out[(m0 + w * 32 + trow) * 64 + s] = v[reg];
            }
        }
        s0 += __shfl_xor(s0, 32, 64);   // join d-halves across lane hi/lo groups
        s1 += __shfl_xor(s1, 32, 64);
        if ((DIRECT_ALL || s >= 64) && l < 32) {
            outg[b_base * 256 + s + COL_OFF]       = s0;
            outg[(b_base + 1) * 256 + s + COL_OFF] = s1;
        }
    }
}

extern "C" void kernel_launch(void* const* d_in, const int* in_sizes, int n_in,
                              void* d_out, int out_size, void* d_ws, size_t ws_size,
                              hipStream_t stream) {
    const float* x  = (const float*)d_in[0];
    const float* W0 = (const float*)d_in[1];
    const float* W1 = (const float*)d_in[2];
    const float* W2 = (const float*)d_in[3];
    const float* b0 = (const float*)d_in[4];
    const float* b1 = (const float*)d_in[5];
    const float* b2 = (const float*)d_in[6];
    float* out = (float*)d_out;

    char* ws = (char*)d_ws;
    float* h1 = (float*)ws;                          // 8 MB (32768 x 64 f32)
    float* h2 = (float*)(ws + (8u << 20));           // 8 MB
    unsigned short* W0h = (unsigned short*)(ws + (16u << 20));   // 6 x 640KB slots
    unsigned short* W0l = W0h + 327680;
    unsigned short* W1h = W0h + 2 * 327680;
    unsigned short* W1l = W0h + 3 * 327680;
    unsigned short* W2h = W0h + 4 * 327680;
    unsigned short* W2l = W0h + 5 * 327680;

    dim3 pb(256), pg((PACKN + 255) / 256);
    pack_w<true ><<<pg, pb, 0, stream>>>(W0, W0h, W0l);
    pack_w<false><<<pg, pb, 0, stream>>>(W1, W1h, W1l);
    pack_w<false><<<pg, pb, 0, stream>>>(W2, W2h, W2l);

    dim3 grid(256), block(256);
    // L0: h = x (padded); direct s in [64,128) -> cols 0..63
    cin_mfma<1, -64, true,  false><<<grid, block, 0, stream>>>(
        x, nullptr, (const uint4*)W0h, (const uint4*)W0l, b0, h1, out);
    // L1: h = h1; direct s in [64,128) -> cols 64..127
    cin_mfma<0,   0, true,  false><<<grid, block, 0, stream>>>(
        x, h1,      (const uint4*)W1h, (const uint4*)W1l, b1, h2, out);
    // L2: h = h2; all 128 s -> cols 128..255
    cin_mfma<0, 128, false, true ><<<grid, block, 0, stream>>>(
        x, h2,      (const uint4*)W2h, (const uint4*)W2l, b2, nullptr, out);
}

// Round 7
// 212.996 us; speedup vs baseline: 3.5546x; 2.1530x over previous
//
#include <hip/hip_runtime.h>

// CIN (xDeepFM) — split-bf16 MFMA v3 for MI355X (gfx950).
//
// out[b,s,d] = relu( sum_{f,g} x[b,f,d]*h[b,g,d]*W[f*Fk+g, s] + b[s] )
// GEMM rows m=(b,d): out_row = z_row * W, z[k] = x[f]*h[g], k = f*64+g
// (FK unified to 64, K = 2496 = 39 f-groups x 64; L0 g>=39 zero-padded).
//
// v3 vs v2 (round 5, 140us/dispatch, MfmaUtil 18%): v2 was latency-bound —
// 1 wave/SIMD and a vmcnt(0)-draining __syncthreads per K16-step exposed full
// L2 latency 156x. v3:
//  (a) 2-term split: (zh+zl)*Wh (drop z*Wl term, err ~0.05 << 0.5 tol) —
//      halves B-LDS reads + staging, -33% MFMA.
//  (b) K64 triple-buffered W staging, counted s_waitcnt vmcnt(4) + raw
//      s_barrier per f-iter (39 barriers; prefetch spans 2 iters, never
//      drained — T3/T4 pattern, m218). Stage-issue AFTER barrier closes the
//      buffer-reuse race: slot (f+2)%3 was last read in iter f-1, which all
//      waves finished before iter f's barrier.
//  (c) h-row hoisted to 32 regs once (kills 2 of 3 per-step LDS reads).
// Wave = 32 rows x 128 cols, 4 waves/block = 128 rows, grid 256 = 1 block/CU.
//
// Round-6 note: GPU never acquired; v3 re-audited (vmcnt ledger, WAR on
// buffer reuse, rule-18 sched_barrier placement) and resubmitted unchanged.

typedef __bf16 bf16x8 __attribute__((ext_vector_type(8)));
typedef float  f32x16 __attribute__((ext_vector_type(16)));

#define NF    39             // f-groups (K64 iters); K16 steps = 156
#define PACKN 319488         // 2496 * 128

// ---- prep: pack W (fp32 [K][128]) -> bf16-hi, 32x32 fragment order ----
// elem idx = ((step16*4 + cf)*64 + lane)*8 + j ; k = step16*16 + (lane>>5)*8 + j ;
// s = cf*32 + (lane&31).  f-group f = steps 4f..4f+3 = uint4s [f*1024,(f+1)*1024).
template<bool L0>
__global__ void pack_w(const float* __restrict__ Wsrc,
                       unsigned short* __restrict__ hi) {
    int idx = blockIdx.x * 256 + threadIdx.x;
    if (idx >= PACKN) return;
    int j    = idx & 7;
    int lane = (idx >> 3) & 63;
    int cf   = (idx >> 9) & 3;
    int step = idx >> 11;
    int k = step * 16 + (lane >> 5) * 8 + j;
    int s = cf * 32 + (lane & 31);
    float v;
    if constexpr (L0) {
        int f = k >> 6, g = k & 63;
        v = (g < 39) ? Wsrc[(f * 39 + g) * 128 + s] : 0.f;
    } else {
        v = Wsrc[k * 128 + s];
    }
    __bf16 h = (__bf16)v;
    hi[idx] = __builtin_bit_cast(unsigned short, h);
}

// ---- main: one CIN layer ----
template<int SRC_X, int COL_OFF, bool WRITE_H, bool DIRECT_ALL>
__launch_bounds__(256, 1)
__global__ void cin_mfma(const float* __restrict__ xg,
                         const float* __restrict__ hg,
                         const uint4* __restrict__ Whi,
                         const float* __restrict__ bg,
                         float* __restrict__ h_out,
                         float* __restrict__ outg) {
    __shared__ __attribute__((aligned(16))) float xs[128][41];  // 21 KB
    __shared__ __attribute__((aligned(16))) float hs[128][68];  // 35 KB
    __shared__ uint4 WL[3][1024];                               // 48 KB: 3 x K64 tile

    const int tid = threadIdx.x;
    const int w   = tid >> 6;           // wave 0..3 -> rows w*32..w*32+31
    const int l   = tid & 63;
    const int m0  = blockIdx.x * 128;   // first (b,d) row; b=m>>4, d=m&15
    const int b0  = m0 >> 4;            // 8 batch elems per block

    // ---- stage x rows: xs[bl*16+d][f] = x[b0+bl, f, d] ----
    for (int idx = tid; idx < 8 * 39 * 16; idx += 256) {
        int bl_ = idx / 624, rem = idx - bl_ * 624;
        int f = rem >> 4, d = rem & 15;
        xs[bl_ * 16 + d][f] = xg[(((b0 + bl_) * 39 + f) << 4) + d];
    }
    // ---- stage h rows: hs[r][g] (L0: from x, g>=39 zero) ----
    if constexpr (SRC_X) {
        for (int idx = tid; idx < 128 * 64; idx += 256) {
            int r = idx >> 6, g = idx & 63;
            hs[r][g] = (g < 39) ? xg[(((b0 + (r >> 4)) * 39 + g) << 4) + (r & 15)] : 0.f;
        }
    } else {
        for (int idx = tid; idx < 128 * 16; idx += 256) {
            int r = idx >> 4, c = idx & 15;
            *reinterpret_cast<float4*>(&hs[r][c * 4]) =
                *reinterpret_cast<const float4*>(&hg[(m0 + r) * 64 + c * 4]);
        }
    }

    // ---- W staging: async global->LDS; 4 loads/wave per K64 buffer ----
    auto stage = [&](int f, int b) {
        #pragma unroll
        for (int i = 0; i < 4; ++i)
            __builtin_amdgcn_global_load_lds(
                (const unsigned int*)(Whi + f * 1024 + i * 256 + w * 64 + l),
                (unsigned int*)&WL[b][i * 256 + w * 64], 16, 0, 0);
    };

    stage(0, 0);
    stage(1, 1);
    __syncthreads();        // one-time full drain: xs/hs stores + stages 0,1

    const int r    = l & 31;            // A row in tile / C col
    const int hb   = l >> 5;            // k-half select
    const int hrow = w * 32 + r;

    // ---- hoist this lane's h values for all 4 sub-steps into 32 regs ----
    float hr[4][8];
    #pragma unroll
    for (int sub = 0; sub < 4; ++sub) {
        float4 a = *reinterpret_cast<const float4*>(&hs[hrow][sub * 16 + hb * 8]);
        float4 bq = *reinterpret_cast<const float4*>(&hs[hrow][sub * 16 + hb * 8 + 4]);
        hr[sub][0] = a.x;  hr[sub][1] = a.y;  hr[sub][2] = a.z;  hr[sub][3] = a.w;
        hr[sub][4] = bq.x; hr[sub][5] = bq.y; hr[sub][6] = bq.z; hr[sub][7] = bq.w;
    }

    f32x16 acc[4];
    #pragma unroll
    for (int c = 0; c < 4; ++c)
        #pragma unroll
        for (int i = 0; i < 16; ++i) acc[c][i] = 0.f;

    // ---- body: one f-group (K=64) from buffer cb ----
    auto body = [&](int f, int cb) {
        float xv = xs[hrow][f];
        #pragma unroll
        for (int sub = 0; sub < 4; ++sub) {
            bf16x8 ah, al;
            #pragma unroll
            for (int j = 0; j < 8; ++j) {
                float p = xv * hr[sub][j];
                __bf16 ph = (__bf16)p;
                ah[j] = ph;
                al[j] = (__bf16)(p - (float)ph);
            }
            #pragma unroll
            for (int cf = 0; cf < 4; ++cf) {
                bf16x8 bh = __builtin_bit_cast(bf16x8, WL[cb][(sub * 4 + cf) * 64 + l]);
                acc[cf] = __builtin_amdgcn_mfma_f32_32x32x16_bf16(ah, bh, acc[cf], 0, 0, 0);
                acc[cf] = __builtin_amdgcn_mfma_f32_32x32x16_bf16(al, bh, acc[cf], 0, 0, 0);
            }
        }
    };

    // ---- main loop: wait own stage(f) -> barrier -> issue stage(f+2) -> compute ----
    int cb = 0;
    for (int f = 0; f < NF - 1; ++f) {
        asm volatile("s_waitcnt vmcnt(4)" ::: "memory");   // stage(f) retired
        __builtin_amdgcn_s_barrier();                      // published to all waves
        __builtin_amdgcn_sched_barrier(0);
        if (f <= NF - 3) stage(f + 2, cb >= 1 ? cb - 1 : cb + 2);
        body(f, cb);
        cb = (cb == 2) ? 0 : cb + 1;
    }
    asm volatile("s_waitcnt vmcnt(0)" ::: "memory");       // last buffer
    __builtin_amdgcn_s_barrier();
    __builtin_amdgcn_sched_barrier(0);
    body(NF - 1, cb);

    // ---- epilogue (verified round 5). C/D 32x32 map (m74/m101):
    // col = lane&31, row = (reg&3) + 8*(reg>>2) + 4*(lane>>5). ----
    const int b_base = b0 + w * 2;
    #pragma unroll
    for (int cf = 0; cf < 4; ++cf) {
        int s = cf * 32 + r;
        float bias = bg[s];
        float v[16], s0 = 0.f, s1 = 0.f;
        #pragma unroll
        for (int reg = 0; reg < 16; ++reg) {
            float vv = fmaxf(acc[cf][reg] + bias, 0.f);
            v[reg] = vv;
            if (reg < 8) s0 += vv; else s1 += vv;
        }
        if (WRITE_H && s < 64) {
            #pragma unroll
            for (int reg = 0; reg < 16; ++reg) {
                int trow = (reg & 3) + 8 * (reg >> 2) + 4 * hb;
                h_out[(m0 + w * 32 + trow) * 64 + s] = v[reg];
            }
        }
        s0 += __shfl_xor(s0, 32, 64);   // join d-halves across lane hi/lo groups
        s1 += __shfl_xor(s1, 32, 64);
        if ((DIRECT_ALL || s >= 64) && l < 32) {
            outg[b_base * 256 + s + COL_OFF]       = s0;
            outg[(b_base + 1) * 256 + s + COL_OFF] = s1;
        }
    }
}

extern "C" void kernel_launch(void* const* d_in, const int* in_sizes, int n_in,
                              void* d_out, int out_size, void* d_ws, size_t ws_size,
                              hipStream_t stream) {
    const float* x  = (const float*)d_in[0];
    const float* W0 = (const float*)d_in[1];
    const float* W1 = (const float*)d_in[2];
    const float* W2 = (const float*)d_in[3];
    const float* b0 = (const float*)d_in[4];
    const float* b1 = (const float*)d_in[5];
    const float* b2 = (const float*)d_in[6];
    float* out = (float*)d_out;

    char* ws = (char*)d_ws;
    float* h1 = (float*)ws;                          // 8 MB (32768 x 64 f32)
    float* h2 = (float*)(ws + (8u << 20));           // 8 MB
    unsigned short* W0h = (unsigned short*)(ws + (16u << 20));   // 3 x 640KB
    unsigned short* W1h = W0h + 327680;
    unsigned short* W2h = W0h + 2 * 327680;

    dim3 pb(256), pg((PACKN + 255) / 256);
    pack_w<true ><<<pg, pb, 0, stream>>>(W0, W0h);
    pack_w<false><<<pg, pb, 0, stream>>>(W1, W1h);
    pack_w<false><<<pg, pb, 0, stream>>>(W2, W2h);

    dim3 grid(256), block(256);
    // L0: h = x (padded); direct s in [64,128) -> cols 0..63
    cin_mfma<1, -64, true,  false><<<grid, block, 0, stream>>>(
        x, nullptr, (const uint4*)W0h, b0, h1, out);
    // L1: h = h1; direct s in [64,128) -> cols 64..127
    cin_mfma<0,   0, true,  false><<<grid, block, 0, stream>>>(
        x, h1,      (const uint4*)W1h, b1, h2, out);
    // L2: h = h2; all 128 s -> cols 128..255
    cin_mfma<0, 128, false, true ><<<grid, block, 0, stream>>>(
        x, h2,      (const uint4*)W2h, b2, nullptr, out);
}

// Round 9
// 200.286 us; speedup vs baseline: 3.7802x; 1.0635x over previous
//
#include <hip/hip_runtime.h>

// CIN (xDeepFM) — fully-fused split-bf16 MFMA v4 for MI355X (gfx950).
//
// out[b,s,d] = relu( sum_{f,g} x[b,f,d]*h[b,g,d]*W[f*64+g, s] + b[s] )
// Rows m=(b,d) are INDEPENDENT across the whole 3-layer chain -> fuse all
// layers in one kernel; h lives in LDS between layers (kills 16MB/boundary
// of global h traffic that dominated v3's 54us dispatches).
//
// Per block: 128 rows, 4 waves (one 32-row 32x32x16 MFMA tile each), 128 cols.
// Per layer: K = 2496 = 39 f-groups x 64; W pre-packed to bf16 fragment order;
// triple-buffered global_load_lds staging, counted vmcnt(4) + raw s_barrier
// (v3-validated T3/T4 ledger). A-frag (z=x*h, 2-term split zh+zl) built in
// registers by the consuming lane. v4 additions:
//  - B frags hoisted to 16 uint4 regs at iter top (ds_reads batched, reused
//    by both split terms), A-builds before MFMA burst.
//  - MFMA order sub-outer/cf-inner: 4 independent acc chains, same-acc
//    distance 4 insts (~32 cyc) -> no dependent-latency stalls at 1 wave/SIMD.
//  - L0's h comes from xs directly (no hs staging; hs written by epilogues).
//
// Round-8 note: GPU never acquired; v4 re-audited (cross-layer vmcnt ledger,
// WL WAR across layers, hs coverage/ordering, L0 garbage guards, VGPR budget)
// and resubmitted unchanged.

typedef __bf16 bf16x8 __attribute__((ext_vector_type(8)));
typedef float  f32x16 __attribute__((ext_vector_type(16)));

#define NF    39
#define PACKN 319488         // 2496*128 packed ushort per layer
#define PACKB 1248           // pack blocks per layer (1248*256 == PACKN)

// ---- prep: pack all 3 W (fp32 [K][128]) -> bf16-hi fragment order ----
// ushort idx = ((step16*4 + cf)*64 + lane)*8 + j ; k = step16*16+(lane>>5)*8+j ;
// s = cf*32+(lane&31).  f-group f = uint4 range [f*1024,(f+1)*1024).
__global__ void pack_w_all(const float* __restrict__ W0,
                           const float* __restrict__ W1,
                           const float* __restrict__ W2,
                           unsigned short* __restrict__ dst) {
    int bid   = blockIdx.x;
    int layer = bid / PACKB;
    int idx   = (bid - layer * PACKB) * 256 + threadIdx.x;   // < PACKN exactly
    int j    = idx & 7;
    int lane = (idx >> 3) & 63;
    int cf   = (idx >> 9) & 3;
    int step = idx >> 11;
    int k = step * 16 + (lane >> 5) * 8 + j;
    int s = cf * 32 + (lane & 31);
    float v;
    if (layer == 0) {
        int f = k >> 6, g = k & 63;
        v = (g < 39) ? W0[(f * 39 + g) * 128 + s] : 0.f;
    } else if (layer == 1) {
        v = W1[k * 128 + s];
    } else {
        v = W2[k * 128 + s];
    }
    __bf16 h = (__bf16)v;
    dst[layer * PACKN + idx] = __builtin_bit_cast(unsigned short, h);
}

// ---- fused 3-layer CIN ----
__launch_bounds__(256, 1)
__global__ void cin_fused(const float* __restrict__ xg,
                          const uint4* __restrict__ Wp,     // 3 x 39936 uint4
                          const float* __restrict__ b0g,
                          const float* __restrict__ b1g,
                          const float* __restrict__ b2g,
                          float* __restrict__ outg) {
    __shared__ __attribute__((aligned(16))) float xs[128][41];  // 21 KB
    __shared__ __attribute__((aligned(16))) float hs[128][68];  // 35 KB
    __shared__ uint4 WL[3][1024];                               // 48 KB

    const int tid = threadIdx.x;
    const int w   = tid >> 6;           // wave 0..3 -> rows w*32..w*32+31
    const int l   = tid & 63;
    const int m0  = blockIdx.x * 128;   // first (b,d) row; b=m>>4, d=m&15
    const int b0  = m0 >> 4;            // 8 batch elems per block

    // ---- stage x rows once: xs[bl*16+d][f] = x[b0+bl, f, d] ----
    for (int idx = tid; idx < 8 * 39 * 16; idx += 256) {
        int bl_ = idx / 624, rem = idx - bl_ * 624;
        int f = rem >> 4, d = rem & 15;
        xs[bl_ * 16 + d][f] = xg[(((b0 + bl_) * 39 + f) << 4) + d];
    }

    const int r    = l & 31;            // A row in tile / C col
    const int hb   = l >> 5;            // k-half select
    const int hrow = w * 32 + r;
    const int b_base = b0 + w * 2;

    #pragma unroll
    for (int layer = 0; layer < 3; ++layer) {
        const uint4* WB = Wp + layer * (PACKN / 8);
        const float* bp = (layer == 0) ? b0g : ((layer == 1) ? b1g : b2g);

        // ---- staging helper: one K64 f-group -> WL[slot] ----
        auto stage = [&](int f, int slot) {
            #pragma unroll
            for (int i = 0; i < 4; ++i)
                __builtin_amdgcn_global_load_lds(
                    (const unsigned int*)(WB + f * 1024 + i * 256 + w * 64 + l),
                    (unsigned int*)&WL[slot][i * 256 + w * 64], 16, 0, 0);
        };

        stage(0, 0);
        stage(1, 1);
        __syncthreads();    // drains stages; publishes prev-layer hs epilogue / xs

        // ---- hoist this lane's h row (g = sub*16 + hb*8 + jj) ----
        float hr[4][8];
        if (layer == 0) {
            #pragma unroll
            for (int sub = 0; sub < 4; ++sub)
                #pragma unroll
                for (int jj = 0; jj < 8; ++jj) {
                    int g = sub * 16 + hb * 8 + jj;
                    hr[sub][jj] = (g < 39) ? xs[hrow][g] : 0.f;
                }
        } else {
            #pragma unroll
            for (int sub = 0; sub < 4; ++sub) {
                float4 a = *reinterpret_cast<const float4*>(&hs[hrow][sub * 16 + hb * 8]);
                float4 bq = *reinterpret_cast<const float4*>(&hs[hrow][sub * 16 + hb * 8 + 4]);
                hr[sub][0] = a.x;  hr[sub][1] = a.y;  hr[sub][2] = a.z;  hr[sub][3] = a.w;
                hr[sub][4] = bq.x; hr[sub][5] = bq.y; hr[sub][6] = bq.z; hr[sub][7] = bq.w;
            }
        }

        f32x16 acc[4];
        #pragma unroll
        for (int c = 0; c < 4; ++c)
            #pragma unroll
            for (int i = 0; i < 16; ++i) acc[c][i] = 0.f;

        // ---- body: one f-group; B in regs, A-builds first, 4 indep acc chains ----
        auto body = [&](int f, const uint4* WLb) {
            uint4 B[16];
            #pragma unroll
            for (int i = 0; i < 16; ++i) B[i] = WLb[i * 64 + l];
            float xv = xs[hrow][f];
            bf16x8 ah[4], al[4];
            #pragma unroll
            for (int sub = 0; sub < 4; ++sub)
                #pragma unroll
                for (int jj = 0; jj < 8; ++jj) {
                    float p = xv * hr[sub][jj];
                    __bf16 ph = (__bf16)p;
                    ah[sub][jj] = ph;
                    al[sub][jj] = (__bf16)(p - (float)ph);
                }
            #pragma unroll
            for (int sub = 0; sub < 4; ++sub)
                #pragma unroll
                for (int cf = 0; cf < 4; ++cf)
                    acc[cf] = __builtin_amdgcn_mfma_f32_32x32x16_bf16(
                        ah[sub], __builtin_bit_cast(bf16x8, B[sub * 4 + cf]), acc[cf], 0, 0, 0);
            #pragma unroll
            for (int sub = 0; sub < 4; ++sub)
                #pragma unroll
                for (int cf = 0; cf < 4; ++cf)
                    acc[cf] = __builtin_amdgcn_mfma_f32_32x32x16_bf16(
                        al[sub], __builtin_bit_cast(bf16x8, B[sub * 4 + cf]), acc[cf], 0, 0, 0);
        };

        // ---- K loop: vmcnt(4) retires own stage(f); barrier publishes it ----
        int slot = 0;
        for (int f = 0; f < NF - 1; ++f) {
            asm volatile("s_waitcnt vmcnt(4)" ::: "memory");
            __builtin_amdgcn_s_barrier();
            __builtin_amdgcn_sched_barrier(0);
            if (f <= NF - 3) stage(f + 2, slot >= 1 ? slot - 1 : slot + 2);
            body(f, WL[slot]);
            slot = (slot == 2) ? 0 : slot + 1;
        }
        asm volatile("s_waitcnt vmcnt(0)" ::: "memory");
        __builtin_amdgcn_s_barrier();
        __builtin_amdgcn_sched_barrier(0);
        body(NF - 1, WL[slot]);

        // ---- epilogue: bias+relu; h-part -> hs (LDS); direct -> d_out ----
        // C/D 32x32 map (m74/m101): col=lane&31, row=(reg&3)+8*(reg>>2)+4*(lane>>5)
        #pragma unroll
        for (int cf = 0; cf < 4; ++cf) {
            int s = cf * 32 + r;
            float bias = bp[s];
            float v[16], s0 = 0.f, s1 = 0.f;
            #pragma unroll
            for (int reg = 0; reg < 16; ++reg) {
                float vv = fmaxf(acc[cf][reg] + bias, 0.f);
                v[reg] = vv;
                if (reg < 8) s0 += vv; else s1 += vv;
            }
            if (layer < 2 && s < 64) {
                #pragma unroll
                for (int reg = 0; reg < 16; ++reg) {
                    int trow = (reg & 3) + 8 * (reg >> 2) + 4 * hb;
                    hs[w * 32 + trow][s] = v[reg];
                }
            }
            s0 += __shfl_xor(s0, 32, 64);   // join d-halves across hb groups
            s1 += __shfl_xor(s1, 32, 64);
            int col = (layer == 0) ? (s - 64) : ((layer == 1) ? s : s + 128);
            bool direct = (layer == 2) || (s >= 64);
            if (direct && l < 32) {
                outg[b_base * 256 + col]       = s0;
                outg[(b_base + 1) * 256 + col] = s1;
            }
        }
        // next layer's stage(0/1) only touch WL[0]/WL[1] (last read at f=36/37,
        // both retired before the f=38 barrier); hs reads happen after the
        // next layer's __syncthreads -> no hazards.
    }
}

extern "C" void kernel_launch(void* const* d_in, const int* in_sizes, int n_in,
                              void* d_out, int out_size, void* d_ws, size_t ws_size,
                              hipStream_t stream) {
    const float* x  = (const float*)d_in[0];
    const float* W0 = (const float*)d_in[1];
    const float* W1 = (const float*)d_in[2];
    const float* W2 = (const float*)d_in[3];
    const float* b0 = (const float*)d_in[4];
    const float* b1 = (const float*)d_in[5];
    const float* b2 = (const float*)d_in[6];
    float* out = (float*)d_out;

    unsigned short* Wpk = (unsigned short*)d_ws;     // 3 x PACKN ushort = 1.92 MB

    pack_w_all<<<dim3(3 * PACKB), dim3(256), 0, stream>>>(W0, W1, W2, Wpk);
    cin_fused<<<dim3(256), dim3(256), 0, stream>>>(
        x, (const uint4*)Wpk, b0, b1, b2, out);
}